// Round 17
// baseline (90.765 us; speedup 1.0000x reference)
//
#include <hip/hip_runtime.h>
#include <hip/hip_bf16.h>

typedef short short8 __attribute__((ext_vector_type(8)));
typedef float f32x4 __attribute__((ext_vector_type(4)));
typedef float f32x16 __attribute__((ext_vector_type(16)));
typedef unsigned int u32x4 __attribute__((ext_vector_type(4)));

#define HID 4096
#define CST 68     // f32 LDS row stride for cayley kernel
#define TPW 4      // tokens per wave (persistent loop)

#define LGKM0 do { asm volatile("s_waitcnt lgkmcnt(0)" ::: "memory"); \
                   __builtin_amdgcn_sched_barrier(0); } while (0)

__device__ __forceinline__ unsigned short f2bf(float f) {
    unsigned int u = __float_as_uint(f);
    u = (u + 0x7FFFu + ((u >> 16) & 1u)) >> 16;
    return (unsigned short)u;
}

// f32x4 = row i of SA (64x64, stride CST) times SB columns j0..j0+3
__device__ __forceinline__ f32x4 mm4(const float* SA, const float* SB, int i, int j0) {
    f32x4 acc = {0.f, 0.f, 0.f, 0.f};
#pragma unroll 8
    for (int k = 0; k < 64; ++k) {
        float a = SA[i * CST + k];
        acc += a * *reinterpret_cast<const f32x4*>(SB + k * CST + j0);
    }
    return acc;
}

// ---------- Kernel 1: Cayley (Neumann) + M-build (r10 verbatim; verified) ----------
// plp packed for mfma2 A-role: plp[((mt*4+kt)*64+lane)*8+e]
// mrp packed for mfma1 B-role: mrp[((kt*2+nt)*64+lane)*8+e]
__global__ __launch_bounds__(1024) void cayley_build_kernel(
    const float* __restrict__ rul, const float* __restrict__ rvl, const float* __restrict__ dl,
    const float* __restrict__ rur, const float* __restrict__ rvr, const float* __restrict__ dr,
    const int* __restrict__ invt,
    unsigned short* __restrict__ plp, unsigned short* __restrict__ mrp)
{
    __shared__ __align__(16) float Yw[64 * CST], Aw[64 * CST], Pw[64 * CST];
    __shared__ __align__(16) float Qw[64 * CST], QTw[64 * CST];
    __shared__ float dd[64];

    const float* ru; const float* rv; const float* dv; unsigned short* ob;
    if (blockIdx.x == 0) { ru = rul; rv = rvl; dv = dl; ob = plp; }
    else                 { ru = rur; rv = rvr; dv = dr; ob = mrp; }

    const int tid = threadIdx.x;
    const int i = tid >> 4;
    const int j0 = (tid & 15) << 2;

    for (int pass = 0; pass < 2; ++pass) {
        const float* raw = (pass == 0) ? ru : rv;
#pragma unroll
        for (int q = 0; q < 4; ++q) {
            int j = j0 + q;
            float v = 0.f;
            if (j > i)      v =  raw[i * 64 + j];
            else if (j < i) v = -raw[j * 64 + i];
            Yw[i * CST + j] = 0.5f * v;
        }
        __syncthreads();
        f32x4 a = mm4(Yw, Yw, i, j0);
        __syncthreads();
        *reinterpret_cast<f32x4*>(Aw + i * CST + j0) = a;
        *reinterpret_cast<f32x4*>(Pw + i * CST + j0) =
            a + *reinterpret_cast<const f32x4*>(Yw + i * CST + j0);
        __syncthreads();
        a = mm4(Pw, Aw, i, j0);
        __syncthreads();
        *reinterpret_cast<f32x4*>(Pw + i * CST + j0) += a;
        __syncthreads();
        a = mm4(Aw, Aw, i, j0);
        __syncthreads();
        *reinterpret_cast<f32x4*>(Aw + i * CST + j0) = a;
        __syncthreads();
        a = mm4(Pw, Aw, i, j0);
        __syncthreads();
        f32x4 p = *reinterpret_cast<const f32x4*>(Pw + i * CST + j0) + a;
#pragma unroll
        for (int q = 0; q < 4; ++q) {
            int j = j0 + q;
            float qv = ((i == j) ? 1.f : 0.f) + 2.f * p[q];
            if (pass == 0) Qw[i * CST + j]  = qv;
            else           QTw[j * CST + i] = qv;
        }
        __syncthreads();
    }
    if (tid < 64) { float d = dv[tid]; dd[tid] = (invt[0] != 0) ? (1.0f / d) : d; }
    __syncthreads();

    f32x4 m = {0.f, 0.f, 0.f, 0.f};
#pragma unroll 8
    for (int j = 0; j < 64; ++j) {
        float aa = Qw[i * CST + j] * dd[j];
        m += aa * *reinterpret_cast<const f32x4*>(QTw + j * CST + j0);
    }
    const int kt = i >> 4, hh = (i >> 3) & 1, e = i & 7;
#pragma unroll
    for (int q = 0; q < 4; ++q) {
        int j = j0 + q;
        unsigned short v = f2bf(m[q]);
        int dst;
        if (blockIdx.x == 0)
            dst = (((j >> 5) * 4 + kt) * 64 + (j & 31) + 32 * hh) * 8 + e;
        else
            dst = ((kt * 2 + (j >> 5)) * 64 + (j & 31) + 32 * hh) * 8 + e;
        ob[dst] = v;
    }
}

// ---------- Kernel 2: persistent-wave pipelined kron (r16 body, looped) ----------
// 512 blocks (2/CU), 4 waves/block, TPW=4 tokens/wave.
// ds staged once to LDS (16KB/block). Per iteration:
//   wait loads(t) [vmcnt(16): 16 wide stores + 16 loads < 63 -> NEVER drains]
//   phase A consumes X landing regs -> bf16 swizzled tile
//   ISSUE loads(t+1) into freed landing buffer  (prefetch hides HBM latency)
//   mfma1 -> pack -> permlane (r10-verified) -> mfma2
//   LDS-transposed epilogue -> 16 x 1KB fully-contiguous stores (r16-verified)
__global__ __launch_bounds__(256, 2) void kron_kernel(
    const float* __restrict__ inp, const float* __restrict__ ds,
    const unsigned short* __restrict__ plp, const unsigned short* __restrict__ mrp,
    const int* __restrict__ invt, float* __restrict__ out, int ntok)
{
    __shared__ __align__(16) unsigned char sbuf[4][8192];
    __shared__ __align__(16) float dsb[4096];
    const int w = threadIdx.x >> 6;
    const int lane = threadIdx.x & 63;
    const int r = lane & 31;
    const int h = lane >> 5;
    unsigned char* S = sbuf[w];
    const bool inv = (invt[0] != 0);

    // stage ds once (coalesced), inversion pre-applied
    for (int i = threadIdx.x; i < 1024; i += 256) {
        f32x4 d = *reinterpret_cast<const f32x4*>(ds + i * 4);
        if (inv) {
#pragma unroll
            for (int e = 0; e < 4; ++e) d[e] = 1.0f / d[e];
        }
        *reinterpret_cast<f32x4*>(dsb + i * 4) = d;
    }

    // persistent table fragments
    short8 b1[8], a2[8];
#pragma unroll
    for (int kt = 0; kt < 4; ++kt)
#pragma unroll
        for (int nt = 0; nt < 2; ++nt)
            b1[kt * 2 + nt] = *reinterpret_cast<const short8*>(
                mrp + ((kt * 2 + nt) * 64 + lane) * 8);
#pragma unroll
    for (int mt = 0; mt < 2; ++mt)
#pragma unroll
        for (int kt = 0; kt < 4; ++kt)
            a2[mt * 4 + kt] = *reinterpret_cast<const short8*>(
                plp + ((mt * 4 + kt) * 64 + lane) * 8);
    __syncthreads();

    const int t0 = (blockIdx.x * 4 + w) * TPW;
    if (t0 >= ntok) return;

    // prologue: load token t0 into landing buffer (16 x f32x4, contiguous 2KB/pair)
    f32x4 xb[16];
    {
        const float* xt = inp + (size_t)t0 * HID;
#pragma unroll
        for (int s = 0; s < 8; ++s) {
            xb[2 * s]     = *reinterpret_cast<const f32x4*>(xt + s * 512 + lane * 8);
            xb[2 * s + 1] = *reinterpret_cast<const f32x4*>(xt + s * 512 + lane * 8 + 4);
        }
    }

    for (int it = 0; it < TPW; ++it) {
        const int t = t0 + it;
        if (t >= ntok) break;

        // ---- Phase A: consume landing regs (+LDS ds) -> swizzled bf16 tile ----
#pragma unroll
        for (int s = 0; s < 8; ++s) {
            f32x4 d0 = *reinterpret_cast<const f32x4*>(dsb + s * 512 + lane * 8);
            f32x4 d1 = *reinterpret_cast<const f32x4*>(dsb + s * 512 + lane * 8 + 4);
            f32x4 x0 = xb[2 * s] * d0;
            f32x4 x1 = xb[2 * s + 1] * d1;
            short8 f;
#pragma unroll
            for (int e = 0; e < 4; ++e) {
                f[e]     = (short)f2bf(x0[e]);
                f[e + 4] = (short)f2bf(x1[e]);
            }
            const int m = s * 8 + (lane >> 3);
            const int c = lane & 7;
            *reinterpret_cast<short8*>(S + ((m * 8 + (c ^ (m & 7))) << 4)) = f;
        }

        // ---- issue next token's loads into the freed landing buffer ----
        if (it + 1 < TPW && t + 1 < ntok) {
            const float* xt = inp + (size_t)(t + 1) * HID;
#pragma unroll
            for (int s = 0; s < 8; ++s) {
                xb[2 * s]     = *reinterpret_cast<const f32x4*>(xt + s * 512 + lane * 8);
                xb[2 * s + 1] = *reinterpret_cast<const f32x4*>(xt + s * 512 + lane * 8 + 4);
            }
        }
        LGKM0;   // tile writes visible for fragment reads

        // ---- Phase B+C: mfma1 -> pack -> permlane swap (r10-verified) ----
        unsigned int zs[4][8];
#pragma unroll
        for (int nt = 0; nt < 2; ++nt) {
#pragma unroll
            for (int mt = 0; mt < 2; ++mt) {
                short8 a1[4];
#pragma unroll
                for (int kt = 0; kt < 4; ++kt)
                    a1[kt] = *reinterpret_cast<const short8*>(
                        S + (((32 * mt + r) * 8 + ((2 * kt + h) ^ (r & 7))) << 4));
                f32x16 acc = {0.f};
#pragma unroll
                for (int kt = 0; kt < 4; ++kt)
                    acc = __builtin_amdgcn_mfma_f32_32x32x16_bf16(a1[kt], b1[kt * 2 + nt], acc, 0, 0, 0);
                unsigned int q[8];
#pragma unroll
                for (int p = 0; p < 8; ++p)
                    q[p] = (unsigned int)f2bf(acc[2 * p]) |
                           ((unsigned int)f2bf(acc[2 * p + 1]) << 16);
                auto s02 = __builtin_amdgcn_permlane32_swap(q[0], q[2], false, false);
                auto s13 = __builtin_amdgcn_permlane32_swap(q[1], q[3], false, false);
                auto s46 = __builtin_amdgcn_permlane32_swap(q[4], q[6], false, false);
                auto s57 = __builtin_amdgcn_permlane32_swap(q[5], q[7], false, false);
                unsigned int* z = zs[mt * 2 + nt];
                z[0] = s02[0]; z[1] = s13[0]; z[2] = s02[1]; z[3] = s13[1];
                z[4] = s46[0]; z[5] = s57[0]; z[6] = s46[1]; z[7] = s57[1];
            }
        }
        LGKM0;   // all tile reads retired; tile dead -> reuse as Y scratch

        // ---- Phase D: mfma2 + LDS transpose + 1KB-contiguous stores (r16) ----
        float* Lf = reinterpret_cast<float*>(S);
        float* op = out + (size_t)t * HID;
#pragma unroll
        for (int mt2 = 0; mt2 < 2; ++mt2) {
#pragma unroll
            for (int nt2 = 0; nt2 < 2; ++nt2) {
                f32x16 y = {0.f};
#pragma unroll
                for (int kt2 = 0; kt2 < 4; ++kt2) {
                    const unsigned int* z = zs[(kt2 >> 1) * 2 + nt2];
                    const int kb = (kt2 & 1) * 4;
                    union { u32x4 u; short8 s; } cv;
                    cv.u[0] = z[kb + 0]; cv.u[1] = z[kb + 1];
                    cv.u[2] = z[kb + 2]; cv.u[3] = z[kb + 3];
                    y = __builtin_amdgcn_mfma_f32_32x32x16_bf16(a2[mt2 * 4 + kt2], cv.s, y, 0, 0, 0);
                }
#pragma unroll
                for (int g = 0; g < 16; ++g) {
                    const int kk = (g & 3) + 8 * (g >> 2) + 4 * h;
                    const int c  = 32 * nt2 + r;
                    Lf[(kk * 16 + ((c >> 2) ^ (kk & 15))) * 4 + (c & 3)] = y[g];
                }
            }
            LGKM0;   // Y half fully in LDS
#pragma unroll
            for (int s = 0; s < 8; ++s) {
                const int f  = s * 64 + lane;
                const int kk = f >> 4;
                const int cg = f & 15;
                f32x4 v = *reinterpret_cast<const f32x4*>(
                    Lf + (kk * 16 + (cg ^ (kk & 15))) * 4);
                *reinterpret_cast<f32x4*>(op + (32 * mt2 + kk) * 64 + cg * 4) = v;
            }
            LGKM0;   // readback retired before tile reuse
        }
    }
}

extern "C" void kernel_launch(void* const* d_in, const int* in_sizes, int n_in,
                              void* d_out, int out_size, void* d_ws, size_t ws_size,
                              hipStream_t stream) {
    const float* inp = (const float*)d_in[0];
    const float* rul = (const float*)d_in[1];
    const float* rvl = (const float*)d_in[2];
    const float* dl  = (const float*)d_in[3];
    const float* rur = (const float*)d_in[4];
    const float* rvr = (const float*)d_in[5];
    const float* dr  = (const float*)d_in[6];
    const float* ds  = (const float*)d_in[7];
    const int*   invt = (const int*)d_in[8];
    float* out = (float*)d_out;

    unsigned short* plp = (unsigned short*)d_ws;   // 4096 bf16, A-role packed PL
    unsigned short* mrp = plp + 4096;              // 4096 bf16, B-role packed MR

    const int ntok = in_sizes[0] / HID;

    hipLaunchKernelGGL(cayley_build_kernel, dim3(2), dim3(1024), 0, stream,
                       rul, rvl, dl, rur, rvr, dr, invt, plp, mrp);
    const int tpb = 4 * TPW;   // 4 waves x TPW tokens
    const int nblk = (ntok + tpb - 1) / tpb;
    hipLaunchKernelGGL(kron_kernel, dim3(nblk), dim3(256), 0, stream,
                       inp, ds, plp, mrp, invt, out, ntok);
}

// Round 18
// 88.801 us; speedup vs baseline: 1.0221x; 1.0221x over previous
//
#include <hip/hip_runtime.h>
#include <hip/hip_bf16.h>

typedef short short8 __attribute__((ext_vector_type(8)));
typedef float f32x4 __attribute__((ext_vector_type(4)));
typedef float f32x16 __attribute__((ext_vector_type(16)));
typedef unsigned int u32x4 __attribute__((ext_vector_type(4)));

#define HID 4096
#define CST 68     // f32 LDS row stride for cayley kernel
#define TPW 2      // tokens per wave (pipelined); 4 waves/block -> 256 blocks = 1/CU

#define LGKM0 do { asm volatile("s_waitcnt lgkmcnt(0)" ::: "memory"); \
                   __builtin_amdgcn_sched_barrier(0); } while (0)

__device__ __forceinline__ unsigned short f2bf(float f) {
    unsigned int u = __float_as_uint(f);
    u = (u + 0x7FFFu + ((u >> 16) & 1u)) >> 16;
    return (unsigned short)u;
}

// f32x4 = row i of SA (64x64, stride CST) times SB columns j0..j0+3
__device__ __forceinline__ f32x4 mm4(const float* SA, const float* SB, int i, int j0) {
    f32x4 acc = {0.f, 0.f, 0.f, 0.f};
#pragma unroll 8
    for (int k = 0; k < 64; ++k) {
        float a = SA[i * CST + k];
        acc += a * *reinterpret_cast<const f32x4*>(SB + k * CST + j0);
    }
    return acc;
}

// ---------- Kernel 1: Cayley (Neumann) + M-build (verified r10/r16) ----------
// plp packed for mfma2 A-role: plp[((mt*4+kt)*64+lane)*8+e]
// mrp packed for mfma1 B-role: mrp[((kt*2+nt)*64+lane)*8+e]
__global__ __launch_bounds__(1024) void cayley_build_kernel(
    const float* __restrict__ rul, const float* __restrict__ rvl, const float* __restrict__ dl,
    const float* __restrict__ rur, const float* __restrict__ rvr, const float* __restrict__ dr,
    const int* __restrict__ invt,
    unsigned short* __restrict__ plp, unsigned short* __restrict__ mrp)
{
    __shared__ __align__(16) float Yw[64 * CST], Aw[64 * CST], Pw[64 * CST];
    __shared__ __align__(16) float Qw[64 * CST], QTw[64 * CST];
    __shared__ float dd[64];

    const float* ru; const float* rv; const float* dv; unsigned short* ob;
    if (blockIdx.x == 0) { ru = rul; rv = rvl; dv = dl; ob = plp; }
    else                 { ru = rur; rv = rvr; dv = dr; ob = mrp; }

    const int tid = threadIdx.x;
    const int i = tid >> 4;
    const int j0 = (tid & 15) << 2;

    for (int pass = 0; pass < 2; ++pass) {
        const float* raw = (pass == 0) ? ru : rv;
#pragma unroll
        for (int q = 0; q < 4; ++q) {
            int j = j0 + q;
            float v = 0.f;
            if (j > i)      v =  raw[i * 64 + j];
            else if (j < i) v = -raw[j * 64 + i];
            Yw[i * CST + j] = 0.5f * v;
        }
        __syncthreads();
        f32x4 a = mm4(Yw, Yw, i, j0);
        __syncthreads();
        *reinterpret_cast<f32x4*>(Aw + i * CST + j0) = a;
        *reinterpret_cast<f32x4*>(Pw + i * CST + j0) =
            a + *reinterpret_cast<const f32x4*>(Yw + i * CST + j0);
        __syncthreads();
        a = mm4(Pw, Aw, i, j0);
        __syncthreads();
        *reinterpret_cast<f32x4*>(Pw + i * CST + j0) += a;
        __syncthreads();
        a = mm4(Aw, Aw, i, j0);
        __syncthreads();
        *reinterpret_cast<f32x4*>(Aw + i * CST + j0) = a;
        __syncthreads();
        a = mm4(Pw, Aw, i, j0);
        __syncthreads();
        f32x4 p = *reinterpret_cast<const f32x4*>(Pw + i * CST + j0) + a;
#pragma unroll
        for (int q = 0; q < 4; ++q) {
            int j = j0 + q;
            float qv = ((i == j) ? 1.f : 0.f) + 2.f * p[q];
            if (pass == 0) Qw[i * CST + j]  = qv;
            else           QTw[j * CST + i] = qv;
        }
        __syncthreads();
    }
    if (tid < 64) { float d = dv[tid]; dd[tid] = (invt[0] != 0) ? (1.0f / d) : d; }
    __syncthreads();

    f32x4 m = {0.f, 0.f, 0.f, 0.f};
#pragma unroll 8
    for (int j = 0; j < 64; ++j) {
        float aa = Qw[i * CST + j] * dd[j];
        m += aa * *reinterpret_cast<const f32x4*>(QTw + j * CST + j0);
    }
    const int kt = i >> 4, hh = (i >> 3) & 1, e = i & 7;
#pragma unroll
    for (int q = 0; q < 4; ++q) {
        int j = j0 + q;
        unsigned short v = f2bf(m[q]);
        int dst;
        if (blockIdx.x == 0)
            dst = (((j >> 5) * 4 + kt) * 64 + (j & 31) + 32 * hh) * 8 + e;
        else
            dst = ((kt * 2 + (j >> 5)) * 64 + (j & 31) + 32 * hh) * 8 + e;
        ob[dst] = v;
    }
}

// ---------- Kernel 2: persistent-wave pipelined kron, FULL grid coverage ----------
// 256 blocks (1/CU), 4 waves/block, TPW=2 tokens/wave, prefetch depth 1.
// r17 structure verbatim (2x per-CU throughput measured at half-grid);
// only change: grid covers all 256 CUs + prologue X load issued FIRST
// (cold HBM latency overlaps table loads + ds staging + syncthreads).
__global__ __launch_bounds__(256, 2) void kron_kernel(
    const float* __restrict__ inp, const float* __restrict__ ds,
    const unsigned short* __restrict__ plp, const unsigned short* __restrict__ mrp,
    const int* __restrict__ invt, float* __restrict__ out, int ntok)
{
    __shared__ __align__(16) unsigned char sbuf[4][8192];
    __shared__ __align__(16) float dsb[4096];
    const int w = threadIdx.x >> 6;
    const int lane = threadIdx.x & 63;
    const int r = lane & 31;
    const int h = lane >> 5;
    unsigned char* S = sbuf[w];
    const bool inv = (invt[0] != 0);

    const int t0 = (blockIdx.x * 4 + w) * TPW;

    // prologue: issue token t0's loads FIRST (latency overlaps everything below)
    f32x4 xb[16];
    if (t0 < ntok) {
        const float* xt = inp + (size_t)t0 * HID;
#pragma unroll
        for (int s = 0; s < 8; ++s) {
            xb[2 * s]     = *reinterpret_cast<const f32x4*>(xt + s * 512 + lane * 8);
            xb[2 * s + 1] = *reinterpret_cast<const f32x4*>(xt + s * 512 + lane * 8 + 4);
        }
    }

    // stage ds once (coalesced), inversion pre-applied
    for (int i = threadIdx.x; i < 1024; i += 256) {
        f32x4 d = *reinterpret_cast<const f32x4*>(ds + i * 4);
        if (inv) {
#pragma unroll
            for (int e = 0; e < 4; ++e) d[e] = 1.0f / d[e];
        }
        *reinterpret_cast<f32x4*>(dsb + i * 4) = d;
    }

    // persistent table fragments
    short8 b1[8], a2[8];
#pragma unroll
    for (int kt = 0; kt < 4; ++kt)
#pragma unroll
        for (int nt = 0; nt < 2; ++nt)
            b1[kt * 2 + nt] = *reinterpret_cast<const short8*>(
                mrp + ((kt * 2 + nt) * 64 + lane) * 8);
#pragma unroll
    for (int mt = 0; mt < 2; ++mt)
#pragma unroll
        for (int kt = 0; kt < 4; ++kt)
            a2[mt * 4 + kt] = *reinterpret_cast<const short8*>(
                plp + ((mt * 4 + kt) * 64 + lane) * 8);
    __syncthreads();

    if (t0 >= ntok) return;

    for (int it = 0; it < TPW; ++it) {
        const int t = t0 + it;
        if (t >= ntok) break;

        // ---- Phase A: consume landing regs (+LDS ds) -> swizzled bf16 tile ----
#pragma unroll
        for (int s = 0; s < 8; ++s) {
            f32x4 d0 = *reinterpret_cast<const f32x4*>(dsb + s * 512 + lane * 8);
            f32x4 d1 = *reinterpret_cast<const f32x4*>(dsb + s * 512 + lane * 8 + 4);
            f32x4 x0 = xb[2 * s] * d0;
            f32x4 x1 = xb[2 * s + 1] * d1;
            short8 f;
#pragma unroll
            for (int e = 0; e < 4; ++e) {
                f[e]     = (short)f2bf(x0[e]);
                f[e + 4] = (short)f2bf(x1[e]);
            }
            const int m = s * 8 + (lane >> 3);
            const int c = lane & 7;
            *reinterpret_cast<short8*>(S + ((m * 8 + (c ^ (m & 7))) << 4)) = f;
        }

        // ---- issue next token's loads into the freed landing buffer ----
        if (it + 1 < TPW && t + 1 < ntok) {
            const float* xt = inp + (size_t)(t + 1) * HID;
#pragma unroll
            for (int s = 0; s < 8; ++s) {
                xb[2 * s]     = *reinterpret_cast<const f32x4*>(xt + s * 512 + lane * 8);
                xb[2 * s + 1] = *reinterpret_cast<const f32x4*>(xt + s * 512 + lane * 8 + 4);
            }
        }
        LGKM0;   // tile writes visible for fragment reads

        // ---- Phase B+C: mfma1 -> pack -> permlane swap (r10-verified) ----
        unsigned int zs[4][8];
#pragma unroll
        for (int nt = 0; nt < 2; ++nt) {
#pragma unroll
            for (int mt = 0; mt < 2; ++mt) {
                short8 a1[4];
#pragma unroll
                for (int kt = 0; kt < 4; ++kt)
                    a1[kt] = *reinterpret_cast<const short8*>(
                        S + (((32 * mt + r) * 8 + ((2 * kt + h) ^ (r & 7))) << 4));
                f32x16 acc = {0.f};
#pragma unroll
                for (int kt = 0; kt < 4; ++kt)
                    acc = __builtin_amdgcn_mfma_f32_32x32x16_bf16(a1[kt], b1[kt * 2 + nt], acc, 0, 0, 0);
                unsigned int q[8];
#pragma unroll
                for (int p = 0; p < 8; ++p)
                    q[p] = (unsigned int)f2bf(acc[2 * p]) |
                           ((unsigned int)f2bf(acc[2 * p + 1]) << 16);
                auto s02 = __builtin_amdgcn_permlane32_swap(q[0], q[2], false, false);
                auto s13 = __builtin_amdgcn_permlane32_swap(q[1], q[3], false, false);
                auto s46 = __builtin_amdgcn_permlane32_swap(q[4], q[6], false, false);
                auto s57 = __builtin_amdgcn_permlane32_swap(q[5], q[7], false, false);
                unsigned int* z = zs[mt * 2 + nt];
                z[0] = s02[0]; z[1] = s13[0]; z[2] = s02[1]; z[3] = s13[1];
                z[4] = s46[0]; z[5] = s57[0]; z[6] = s46[1]; z[7] = s57[1];
            }
        }
        LGKM0;   // all tile reads retired; tile dead -> reuse as Y scratch

        // ---- Phase D: mfma2 + LDS transpose + 1KB-contiguous stores (r16) ----
        float* Lf = reinterpret_cast<float*>(S);
        float* op = out + (size_t)t * HID;
#pragma unroll
        for (int mt2 = 0; mt2 < 2; ++mt2) {
#pragma unroll
            for (int nt2 = 0; nt2 < 2; ++nt2) {
                f32x16 y = {0.f};
#pragma unroll
                for (int kt2 = 0; kt2 < 4; ++kt2) {
                    const unsigned int* z = zs[(kt2 >> 1) * 2 + nt2];
                    const int kb = (kt2 & 1) * 4;
                    union { u32x4 u; short8 s; } cv;
                    cv.u[0] = z[kb + 0]; cv.u[1] = z[kb + 1];
                    cv.u[2] = z[kb + 2]; cv.u[3] = z[kb + 3];
                    y = __builtin_amdgcn_mfma_f32_32x32x16_bf16(a2[mt2 * 4 + kt2], cv.s, y, 0, 0, 0);
                }
#pragma unroll
                for (int g = 0; g < 16; ++g) {
                    const int kk = (g & 3) + 8 * (g >> 2) + 4 * h;
                    const int c  = 32 * nt2 + r;
                    Lf[(kk * 16 + ((c >> 2) ^ (kk & 15))) * 4 + (c & 3)] = y[g];
                }
            }
            LGKM0;   // Y half fully in LDS
#pragma unroll
            for (int s = 0; s < 8; ++s) {
                const int f  = s * 64 + lane;
                const int kk = f >> 4;
                const int cg = f & 15;
                f32x4 v = *reinterpret_cast<const f32x4*>(
                    Lf + (kk * 16 + (cg ^ (kk & 15))) * 4);
                *reinterpret_cast<f32x4*>(op + (32 * mt2 + kk) * 64 + cg * 4) = v;
            }
            LGKM0;   // readback retired before tile reuse
        }
    }
}

extern "C" void kernel_launch(void* const* d_in, const int* in_sizes, int n_in,
                              void* d_out, int out_size, void* d_ws, size_t ws_size,
                              hipStream_t stream) {
    const float* inp = (const float*)d_in[0];
    const float* rul = (const float*)d_in[1];
    const float* rvl = (const float*)d_in[2];
    const float* dl  = (const float*)d_in[3];
    const float* rur = (const float*)d_in[4];
    const float* rvr = (const float*)d_in[5];
    const float* dr  = (const float*)d_in[6];
    const float* ds  = (const float*)d_in[7];
    const int*   invt = (const int*)d_in[8];
    float* out = (float*)d_out;

    unsigned short* plp = (unsigned short*)d_ws;   // 4096 bf16, A-role packed PL
    unsigned short* mrp = plp + 4096;              // 4096 bf16, B-role packed MR

    const int ntok = in_sizes[0] / HID;

    hipLaunchKernelGGL(cayley_build_kernel, dim3(2), dim3(1024), 0, stream,
                       rul, rvl, dl, rur, rvr, dr, invt, plp, mrp);
    const int tpb = 4 * TPW;   // 4 waves x TPW tokens = 8 tokens/block
    const int nblk = (ntok + tpb - 1) / tpb;   // 2048 -> 256 blocks = 1/CU
    hipLaunchKernelGGL(kron_kernel, dim3(nblk), dim3(256), 0, stream,
                       inp, ds, plp, mrp, invt, out, ntok);
}

// Round 19
// 77.525 us; speedup vs baseline: 1.1708x; 1.1455x over previous
//
#include <hip/hip_runtime.h>
#include <hip/hip_bf16.h>

typedef short short8 __attribute__((ext_vector_type(8)));
typedef float f32x4 __attribute__((ext_vector_type(4)));
typedef float f32x16 __attribute__((ext_vector_type(16)));
typedef unsigned int u32x4 __attribute__((ext_vector_type(4)));

#define HID 4096
#define CST 68     // f32 LDS row stride for cayley kernel

#define LGKM0 do { asm volatile("s_waitcnt lgkmcnt(0)" ::: "memory"); \
                   __builtin_amdgcn_sched_barrier(0); } while (0)

__device__ __forceinline__ unsigned short f2bf(float f) {
    unsigned int u = __float_as_uint(f);
    u = (u + 0x7FFFu + ((u >> 16) & 1u)) >> 16;
    return (unsigned short)u;
}

// f32x4 = row i of SA (64x64, stride CST) times SB columns j0..j0+3
__device__ __forceinline__ f32x4 mm4(const float* SA, const float* SB, int i, int j0) {
    f32x4 acc = {0.f, 0.f, 0.f, 0.f};
#pragma unroll 8
    for (int k = 0; k < 64; ++k) {
        float a = SA[i * CST + k];
        acc += a * *reinterpret_cast<const f32x4*>(SB + k * CST + j0);
    }
    return acc;
}

// ---------- Kernel 1: Cayley (Neumann) + M-build (r10/r16 verbatim; verified) ----------
// plp packed for mfma2 A-role: plp[((mt*4+kt)*64+lane)*8+e]
// mrp packed for mfma1 B-role: mrp[((kt*2+nt)*64+lane)*8+e]
__global__ __launch_bounds__(1024) void cayley_build_kernel(
    const float* __restrict__ rul, const float* __restrict__ rvl, const float* __restrict__ dl,
    const float* __restrict__ rur, const float* __restrict__ rvr, const float* __restrict__ dr,
    const int* __restrict__ invt,
    unsigned short* __restrict__ plp, unsigned short* __restrict__ mrp)
{
    __shared__ __align__(16) float Yw[64 * CST], Aw[64 * CST], Pw[64 * CST];
    __shared__ __align__(16) float Qw[64 * CST], QTw[64 * CST];
    __shared__ float dd[64];

    const float* ru; const float* rv; const float* dv; unsigned short* ob;
    if (blockIdx.x == 0) { ru = rul; rv = rvl; dv = dl; ob = plp; }
    else                 { ru = rur; rv = rvr; dv = dr; ob = mrp; }

    const int tid = threadIdx.x;
    const int i = tid >> 4;
    const int j0 = (tid & 15) << 2;

    for (int pass = 0; pass < 2; ++pass) {
        const float* raw = (pass == 0) ? ru : rv;
#pragma unroll
        for (int q = 0; q < 4; ++q) {
            int j = j0 + q;
            float v = 0.f;
            if (j > i)      v =  raw[i * 64 + j];
            else if (j < i) v = -raw[j * 64 + i];
            Yw[i * CST + j] = 0.5f * v;
        }
        __syncthreads();
        f32x4 a = mm4(Yw, Yw, i, j0);
        __syncthreads();
        *reinterpret_cast<f32x4*>(Aw + i * CST + j0) = a;
        *reinterpret_cast<f32x4*>(Pw + i * CST + j0) =
            a + *reinterpret_cast<const f32x4*>(Yw + i * CST + j0);
        __syncthreads();
        a = mm4(Pw, Aw, i, j0);
        __syncthreads();
        *reinterpret_cast<f32x4*>(Pw + i * CST + j0) += a;
        __syncthreads();
        a = mm4(Aw, Aw, i, j0);
        __syncthreads();
        *reinterpret_cast<f32x4*>(Aw + i * CST + j0) = a;
        __syncthreads();
        a = mm4(Pw, Aw, i, j0);
        __syncthreads();
        f32x4 p = *reinterpret_cast<const f32x4*>(Pw + i * CST + j0) + a;
#pragma unroll
        for (int q = 0; q < 4; ++q) {
            int j = j0 + q;
            float qv = ((i == j) ? 1.f : 0.f) + 2.f * p[q];
            if (pass == 0) Qw[i * CST + j]  = qv;
            else           QTw[j * CST + i] = qv;
        }
        __syncthreads();
    }
    if (tid < 64) { float d = dv[tid]; dd[tid] = (invt[0] != 0) ? (1.0f / d) : d; }
    __syncthreads();

    f32x4 m = {0.f, 0.f, 0.f, 0.f};
#pragma unroll 8
    for (int j = 0; j < 64; ++j) {
        float aa = Qw[i * CST + j] * dd[j];
        m += aa * *reinterpret_cast<const f32x4*>(QTw + j * CST + j0);
    }
    const int kt = i >> 4, hh = (i >> 3) & 1, e = i & 7;
#pragma unroll
    for (int q = 0; q < 4; ++q) {
        int j = j0 + q;
        unsigned short v = f2bf(m[q]);
        int dst;
        if (blockIdx.x == 0)
            dst = (((j >> 5) * 4 + kt) * 64 + (j & 31) + 32 * hh) * 8 + e;
        else
            dst = ((kt * 2 + (j >> 5)) * 64 + (j & 31) + 32 * hh) * 8 + e;
        ob[dst] = v;
    }
}

// ---------- Kernel 2: r16 kron + NONTEMPORAL full-line store epilogue ----------
// Byte-identical to r16 except the 16 x 1KB-contiguous stores are nontemporal:
// out is write-once/never-read, each NT store covers 8 FULL 128B lines ->
// no partial-line amplification (r3's failure mode), and out no longer
// allocates in L2/L3 -> inp stays L3-resident across replays (FETCH -> small),
// writes stream on the 7 TB/s fill-proven path.
__global__ __launch_bounds__(256, 4) void kron_kernel(
    const float* __restrict__ inp, const float* __restrict__ ds,
    const unsigned short* __restrict__ plp, const unsigned short* __restrict__ mrp,
    const int* __restrict__ invt, float* __restrict__ out, int ntok)
{
    __shared__ __align__(16) unsigned char sbuf[4][8192];
    const int w = threadIdx.x >> 6;
    const int lane = threadIdx.x & 63;
    const int r = lane & 31;
    const int h = lane >> 5;
    unsigned char* S = sbuf[w];

    const int t = blockIdx.x * 4 + w;
    if (t >= ntok) return;
    const bool inv = (invt[0] != 0);
    const float* xt = inp + (size_t)t * HID;

    // ---- Phase A: stage Xs (contiguous 2KB loads, swizzled bf16 tile) ----
#pragma unroll
    for (int s = 0; s < 8; ++s) {
        const int fi = s * 512 + lane * 8;
        f32x4 x0 = *reinterpret_cast<const f32x4*>(xt + fi);
        f32x4 x1 = *reinterpret_cast<const f32x4*>(xt + fi + 4);
        f32x4 d0 = *reinterpret_cast<const f32x4*>(ds + fi);
        f32x4 d1 = *reinterpret_cast<const f32x4*>(ds + fi + 4);
        if (inv) {
#pragma unroll
            for (int e = 0; e < 4; ++e) { x0[e] /= d0[e]; x1[e] /= d1[e]; }
        } else {
            x0 *= d0; x1 *= d1;
        }
        short8 f;
#pragma unroll
        for (int e = 0; e < 4; ++e) {
            f[e]     = (short)f2bf(x0[e]);
            f[e + 4] = (short)f2bf(x1[e]);
        }
        const int m = s * 8 + (lane >> 3);
        const int c = lane & 7;
        *reinterpret_cast<short8*>(S + ((m * 8 + (c ^ (m & 7))) << 4)) = f;
    }
    LGKM0;

    // ---- Phase B+C: mfma1 -> pack -> permlane swap into zs (r10-verified) ----
    unsigned int zs[4][8];
#pragma unroll
    for (int nt = 0; nt < 2; ++nt) {
        short8 b1[4];
#pragma unroll
        for (int kt = 0; kt < 4; ++kt)
            b1[kt] = *reinterpret_cast<const short8*>(
                mrp + ((kt * 2 + nt) * 64 + lane) * 8);
#pragma unroll
        for (int mt = 0; mt < 2; ++mt) {
            short8 a1[4];
#pragma unroll
            for (int kt = 0; kt < 4; ++kt)
                a1[kt] = *reinterpret_cast<const short8*>(
                    S + (((32 * mt + r) * 8 + ((2 * kt + h) ^ (r & 7))) << 4));
            f32x16 acc = {0.f};
#pragma unroll
            for (int kt = 0; kt < 4; ++kt)
                acc = __builtin_amdgcn_mfma_f32_32x32x16_bf16(a1[kt], b1[kt], acc, 0, 0, 0);
            unsigned int q[8];
#pragma unroll
            for (int p = 0; p < 8; ++p)
                q[p] = (unsigned int)f2bf(acc[2 * p]) |
                       ((unsigned int)f2bf(acc[2 * p + 1]) << 16);
            auto s02 = __builtin_amdgcn_permlane32_swap(q[0], q[2], false, false);
            auto s13 = __builtin_amdgcn_permlane32_swap(q[1], q[3], false, false);
            auto s46 = __builtin_amdgcn_permlane32_swap(q[4], q[6], false, false);
            auto s57 = __builtin_amdgcn_permlane32_swap(q[5], q[7], false, false);
            unsigned int* z = zs[mt * 2 + nt];
            z[0] = s02[0]; z[1] = s13[0]; z[2] = s02[1]; z[3] = s13[1];
            z[4] = s46[0]; z[5] = s57[0]; z[6] = s46[1]; z[7] = s57[1];
        }
    }
    LGKM0;   // all LDS reads of the X tile retired; tile is dead -> reuse for Y

    // ---- Phase D: mfma2 + LDS transpose + NT 1KB-contiguous stores ----
    float* Lf = reinterpret_cast<float*>(S);
    float* op = out + (size_t)t * HID;
#pragma unroll
    for (int mt2 = 0; mt2 < 2; ++mt2) {
        short8 a2[4];
#pragma unroll
        for (int kt = 0; kt < 4; ++kt)
            a2[kt] = *reinterpret_cast<const short8*>(
                plp + ((mt2 * 4 + kt) * 64 + lane) * 8);
#pragma unroll
        for (int nt2 = 0; nt2 < 2; ++nt2) {
            f32x16 y = {0.f};
#pragma unroll
            for (int kt2 = 0; kt2 < 4; ++kt2) {
                const unsigned int* z = zs[(kt2 >> 1) * 2 + nt2];
                const int kb = (kt2 & 1) * 4;
                union { u32x4 u; short8 s; } cv;
                cv.u[0] = z[kb + 0]; cv.u[1] = z[kb + 1];
                cv.u[2] = z[kb + 2]; cv.u[3] = z[kb + 3];
                y = __builtin_amdgcn_mfma_f32_32x32x16_bf16(a2[kt2], cv.s, y, 0, 0, 0);
            }
#pragma unroll
            for (int g = 0; g < 16; ++g) {
                const int kk = (g & 3) + 8 * (g >> 2) + 4 * h;
                const int c  = 32 * nt2 + r;
                Lf[(kk * 16 + ((c >> 2) ^ (kk & 15))) * 4 + (c & 3)] = y[g];
            }
        }
        LGKM0;   // Y half fully in LDS
        // lane-linear readback + 8 x 1KB fully-contiguous NONTEMPORAL stores
#pragma unroll
        for (int s = 0; s < 8; ++s) {
            const int f  = s * 64 + lane;
            const int kk = f >> 4;
            const int cg = f & 15;
            f32x4 v = *reinterpret_cast<const f32x4*>(
                Lf + (kk * 16 + (cg ^ (kk & 15))) * 4);
            __builtin_nontemporal_store(v,
                reinterpret_cast<f32x4*>(op + (32 * mt2 + kk) * 64 + cg * 4));
        }
        LGKM0;   // readback retired before half-1 overwrites the tile
    }
}

extern "C" void kernel_launch(void* const* d_in, const int* in_sizes, int n_in,
                              void* d_out, int out_size, void* d_ws, size_t ws_size,
                              hipStream_t stream) {
    const float* inp = (const float*)d_in[0];
    const float* rul = (const float*)d_in[1];
    const float* rvl = (const float*)d_in[2];
    const float* dl  = (const float*)d_in[3];
    const float* rur = (const float*)d_in[4];
    const float* rvr = (const float*)d_in[5];
    const float* dr  = (const float*)d_in[6];
    const float* ds  = (const float*)d_in[7];
    const int*   invt = (const int*)d_in[8];
    float* out = (float*)d_out;

    unsigned short* plp = (unsigned short*)d_ws;   // 4096 bf16, A-role packed PL
    unsigned short* mrp = plp + 4096;              // 4096 bf16, B-role packed MR

    const int ntok = in_sizes[0] / HID;

    hipLaunchKernelGGL(cayley_build_kernel, dim3(2), dim3(1024), 0, stream,
                       rul, rvl, dl, rur, rvr, dr, invt, plp, mrp);
    const int nblk = (ntok + 3) / 4;
    hipLaunchKernelGGL(kron_kernel, dim3(nblk), dim3(256), 0, stream,
                       inp, ds, plp, mrp, invt, out, ntok);
}